// Round 15
// baseline (176.147 us; speedup 1.0000x reference)
//
#include <hip/hip_runtime.h>

#define N_NODES 50000
#define N_PAD 50176    // 392 * 128 (gemm grid coverage)
#define N_EDGES 800000
#define C 128
#define CAP 48         // padded bucket capacity; deg ~ Poisson(16), P(>48) ~ 3e-11
#define BUCK_B 391     // bucket blocks: 800000 edges / (256 thr * 8 edges)
#define PACK_B 16      // W-pack blocks (4096 threads)
#define TOBF_B 6250    // tobf16 blocks (1.6M float4 / 256)

typedef unsigned short ushort_t;
typedef unsigned int uint_t;
typedef __attribute__((ext_vector_type(8))) short bf16x8;
typedef __attribute__((ext_vector_type(4))) float f32x4;

// ---------------- fp32 -> bf16 (RNE) ----------------
__device__ __forceinline__ uint_t f2bf(float f) {
    uint_t u = __float_as_uint(f);
    u += 0x7fffu + ((u >> 16) & 1u);
    return u >> 16;
}
__device__ __forceinline__ float bflo(uint_t u) { return __uint_as_float(u << 16); }
__device__ __forceinline__ float bfhi(uint_t u) { return __uint_as_float(u & 0xffff0000u); }

// ---- bucket fill (8 edges/thread, batched atomics) + W-fragment pack ----
__global__ __launch_bounds__(256) void bucketpack_kernel(
    const int* __restrict__ src, const int* __restrict__ dst,
    int* __restrict__ cursor, int* __restrict__ epad,
    const float* __restrict__ W1l, const float* __restrict__ W1r,
    ushort_t* __restrict__ Bp) {
    int b = blockIdx.x;
    if (b < BUCK_B) {
        int i4 = b * 256 + threadIdx.x;       // index into int4 arrays, 2 per thread
        if (i4 < N_EDGES / 8) {
            int4 s0 = ((const int4*)src)[2 * i4];
            int4 s1 = ((const int4*)src)[2 * i4 + 1];
            int4 d0 = ((const int4*)dst)[2 * i4];
            int4 d1 = ((const int4*)dst)[2 * i4 + 1];
            int p0 = atomicAdd(&cursor[d0.x], 1);
            int p1 = atomicAdd(&cursor[d0.y], 1);
            int p2 = atomicAdd(&cursor[d0.z], 1);
            int p3 = atomicAdd(&cursor[d0.w], 1);
            int p4 = atomicAdd(&cursor[d1.x], 1);
            int p5 = atomicAdd(&cursor[d1.y], 1);
            int p6 = atomicAdd(&cursor[d1.z], 1);
            int p7 = atomicAdd(&cursor[d1.w], 1);
            if (p0 < CAP) epad[d0.x * CAP + p0] = s0.x;
            if (p1 < CAP) epad[d0.y * CAP + p1] = s0.y;
            if (p2 < CAP) epad[d0.z * CAP + p2] = s0.z;
            if (p3 < CAP) epad[d0.w * CAP + p3] = s0.w;
            if (p4 < CAP) epad[d1.x * CAP + p4] = s1.x;
            if (p5 < CAP) epad[d1.y * CAP + p5] = s1.y;
            if (p6 < CAP) epad[d1.z * CAP + p6] = s1.z;
            if (p7 < CAP) epad[d1.w * CAP + p7] = s1.w;
        }
    } else {
        // Bp[((nt*8+kk)*64 + lane)*8 + j] = Wcat[kk*32 + (lane>>4)*8 + j][nt*16 + (lane&15)]
        int p = (b - BUCK_B) * 256 + threadIdx.x;   // 0..4095
        int lane = p & 63;
        int pair = p >> 6;          // (nt*8 + kk)
        int kk = pair & 7;
        int nt = pair >> 3;
        int n = lane & 15, quad = lane >> 4;
        int col = nt * 16 + n;
        int k0 = kk * 32 + quad * 8;
        uint_t w[4];
        #pragma unroll
        for (int jj = 0; jj < 4; jj++) {
            int ka = k0 + 2 * jj, kb = k0 + 2 * jj + 1;
            float fa = (ka < C) ? W1l[ka * C + col] : W1r[(ka - C) * C + col];
            float fb = (kb < C) ? W1l[kb * C + col] : W1r[(kb - C) * C + col];
            w[jj] = f2bf(fa) | (f2bf(fb) << 16);
        }
        ((uint4*)(Bp + (size_t)p * 8))[0] = make_uint4(w[0], w[1], w[2], w[3]);
    }
}

// ---- tobf16: pure stream x -> xh ----
__global__ __launch_bounds__(256) void tobf16_kernel(const float* __restrict__ x,
                                                     ushort_t* __restrict__ xh) {
    int i = blockIdx.x * 256 + threadIdx.x;   // one float4 per thread
    float4 v = ((const float4*)x)[i];
    uint_t lo = f2bf(v.x) | (f2bf(v.y) << 16);
    uint_t hi = f2bf(v.z) | (f2bf(v.w) << 16);
    ((uint2*)xh)[i] = make_uint2(lo, hi);
}

// accumulate 8 bf16 (packed in uint4) into a[0..7] (fp32)
__device__ __forceinline__ void bf8_acc(float* a, const uint4 v) {
    a[0] += bflo(v.x); a[1] += bfhi(v.x);
    a[2] += bflo(v.y); a[3] += bfhi(v.y);
    a[4] += bflo(v.z); a[5] += bfhi(v.z);
    a[6] += bflo(v.w); a[7] += bfhi(v.w);
}

// ---------------- gather: msb[n] = mean_{j in N(n)} xh[j]  (bf16 out) ----------------
// 256 threads = 16 node-slots x 16 lanes; lane q covers cols 8q..8q+7 (uint4).
__global__ __launch_bounds__(256) void gather_kernel(const ushort_t* __restrict__ xh,
                                                     const int* __restrict__ cursor,
                                                     const int* __restrict__ epad,
                                                     ushort_t* __restrict__ msb) {
    int t = threadIdx.x;
    int slot = t >> 4, q = t & 15;
    int node = blockIdx.x * 16 + slot;   // 3125 blocks -> exactly 50000
    int d = cursor[node];
    int dd = d < CAP ? d : CAP;
    const int* lst = epad + node * CAP;
    float a[8] = {0,0,0,0,0,0,0,0};
    float b[8] = {0,0,0,0,0,0,0,0};
    int e = 0;
    for (; e + 8 <= dd; e += 8) {
        int s0 = lst[e + 0], s1 = lst[e + 1], s2 = lst[e + 2], s3 = lst[e + 3];
        int s4 = lst[e + 4], s5 = lst[e + 5], s6 = lst[e + 6], s7 = lst[e + 7];
        uint4 v0 = ((const uint4*)(xh + (size_t)s0 * C))[q];
        uint4 v1 = ((const uint4*)(xh + (size_t)s1 * C))[q];
        uint4 v2 = ((const uint4*)(xh + (size_t)s2 * C))[q];
        uint4 v3 = ((const uint4*)(xh + (size_t)s3 * C))[q];
        uint4 v4 = ((const uint4*)(xh + (size_t)s4 * C))[q];
        uint4 v5 = ((const uint4*)(xh + (size_t)s5 * C))[q];
        uint4 v6 = ((const uint4*)(xh + (size_t)s6 * C))[q];
        uint4 v7 = ((const uint4*)(xh + (size_t)s7 * C))[q];
        bf8_acc(a, v0); bf8_acc(b, v1); bf8_acc(a, v2); bf8_acc(b, v3);
        bf8_acc(a, v4); bf8_acc(b, v5); bf8_acc(a, v6); bf8_acc(b, v7);
    }
    for (; e + 4 <= dd; e += 4) {
        int s0 = lst[e + 0], s1 = lst[e + 1], s2 = lst[e + 2], s3 = lst[e + 3];
        uint4 v0 = ((const uint4*)(xh + (size_t)s0 * C))[q];
        uint4 v1 = ((const uint4*)(xh + (size_t)s1 * C))[q];
        uint4 v2 = ((const uint4*)(xh + (size_t)s2 * C))[q];
        uint4 v3 = ((const uint4*)(xh + (size_t)s3 * C))[q];
        bf8_acc(a, v0); bf8_acc(b, v1); bf8_acc(a, v2); bf8_acc(b, v3);
    }
    for (; e < dd; e++) {
        uint4 v = ((const uint4*)(xh + (size_t)lst[e] * C))[q];
        bf8_acc(a, v);
    }
    float inv = 1.0f / fmaxf((float)d, 1.0f);
    uint4 o;
    o.x = f2bf((a[0] + b[0]) * inv) | (f2bf((a[1] + b[1]) * inv) << 16);
    o.y = f2bf((a[2] + b[2]) * inv) | (f2bf((a[3] + b[3]) * inv) << 16);
    o.z = f2bf((a[4] + b[4]) * inv) | (f2bf((a[5] + b[5]) * inv) << 16);
    o.w = f2bf((a[6] + b[6]) * inv) | (f2bf((a[7] + b[7]) * inv) << 16);
    ((uint4*)(msb + (size_t)node * C))[q] = o;
}

// ---------------- gemm (MFMA, LDS-staged B): h = relu([ms|xs]@[W1l;W1r]+b1l) ----------------
__global__ __launch_bounds__(512) void gemm_mfma(
    const ushort_t* __restrict__ msb, const ushort_t* __restrict__ xh,
    const ushort_t* __restrict__ Bp, const float* __restrict__ b1l,
    const float* __restrict__ W2l, const float* __restrict__ W2r,
    const float* __restrict__ b2l, float* __restrict__ z, float* __restrict__ out) {
    __shared__ ushort_t sB[2 * C * C];   // 64 KB
    int t = threadIdx.x;
    #pragma unroll
    for (int i = 0; i < 8; i++)
        ((uint4*)sB)[i * 512 + t] = ((const uint4*)Bp)[i * 512 + t];
    __syncthreads();

    int wid = t >> 6, lane = t & 63;
    int m = lane & 15, quad = lane >> 4;
    int base = blockIdx.x * 128 + wid * 16;   // node base for this wave

    const ushort_t* a_ms = msb + (size_t)(base + m) * C + quad * 8;
    const ushort_t* a_xh = xh  + (size_t)(base + m) * C + quad * 8;
    bf16x8 aw[8];
    #pragma unroll
    for (int kk = 0; kk < 4; kk++) aw[kk]     = *(const bf16x8*)(a_ms + kk * 32);
    #pragma unroll
    for (int kk = 0; kk < 4; kk++) aw[4 + kk] = *(const bf16x8*)(a_xh + kk * 32);

    f32x4 acc[8];
    #pragma unroll
    for (int nt = 0; nt < 8; nt++) acc[nt] = (f32x4){0.f, 0.f, 0.f, 0.f};

    const bf16x8* bp = (const bf16x8*)sB;
    #pragma unroll
    for (int kk = 0; kk < 8; kk++) {
        bf16x8 a = aw[kk];
        #pragma unroll
        for (int nt = 0; nt < 8; nt++) {
            bf16x8 bfr = bp[(nt * 8 + kk) * 64 + lane];   // ds_read_b128
            acc[nt] = __builtin_amdgcn_mfma_f32_16x16x32_bf16(a, bfr, acc[nt], 0, 0, 0);
        }
    }

    float zz0[4] = {0,0,0,0}, zz1[4] = {0,0,0,0};
    float rr0[4] = {0,0,0,0}, rr1[4] = {0,0,0,0};
    #pragma unroll
    for (int nt = 0; nt < 8; nt++) {
        int col = nt * 16 + m;
        float bias = b1l[col];
        float2 wl = ((const float2*)W2l)[col];
        float2 wr = ((const float2*)W2r)[col];
        #pragma unroll
        for (int reg = 0; reg < 4; reg++) {
            float h = fmaxf(acc[nt][reg] + bias, 0.0f);
            zz0[reg] = fmaf(h, wl.x, zz0[reg]);
            zz1[reg] = fmaf(h, wl.y, zz1[reg]);
            rr0[reg] = fmaf(h, wr.x, rr0[reg]);
            rr1[reg] = fmaf(h, wr.y, rr1[reg]);
        }
    }
    float bl0 = b2l[0], bl1 = b2l[1];
    #pragma unroll
    for (int reg = 0; reg < 4; reg++) {
        float a0 = zz0[reg], a1 = zz1[reg], c0 = rr0[reg], c1 = rr1[reg];
        #pragma unroll
        for (int off = 8; off > 0; off >>= 1) {
            a0 += __shfl_down(a0, off, 16);
            a1 += __shfl_down(a1, off, 16);
            c0 += __shfl_down(c0, off, 16);
            c1 += __shfl_down(c1, off, 16);
        }
        if (m == 0) {
            int node = base + quad * 4 + reg;
            if (node < N_NODES) {
                z[node * 2 + 0]   = a0;
                z[node * 2 + 1]   = a1;
                out[node * 2 + 0] = c0 + bl0;
                out[node * 2 + 1] = c1 + bl1;
            }
        }
    }
}

// ---------------- final: out[n] += mean_{j in N(n)} z[j], 16 lanes per node ----------------
__global__ __launch_bounds__(256) void final_kernel(const float* __restrict__ z,
                                                    const int* __restrict__ cursor,
                                                    const int* __restrict__ epad,
                                                    float* __restrict__ out) {
    int t = threadIdx.x;
    int sub = t & 15;
    int node = blockIdx.x * 16 + (t >> 4);   // 3125 blocks
    int d = cursor[node];
    int dd = d < CAP ? d : CAP;
    const int* lst = epad + node * CAP;
    float a0 = 0.0f, a1 = 0.0f;
    for (int e = sub; e < dd; e += 16) {
        float2 v = ((const float2*)z)[lst[e]];
        a0 += v.x; a1 += v.y;
    }
    #pragma unroll
    for (int off = 8; off > 0; off >>= 1) {
        a0 += __shfl_down(a0, off);
        a1 += __shfl_down(a1, off);
    }
    if (sub == 0) {
        float inv = 1.0f / fmaxf((float)d, 1.0f);
        out[node * 2 + 0] += a0 * inv;
        out[node * 2 + 1] += a1 * inv;
    }
}

extern "C" void kernel_launch(void* const* d_in, const int* in_sizes, int n_in,
                              void* d_out, int out_size, void* d_ws, size_t ws_size,
                              hipStream_t stream) {
    const float* x   = (const float*)d_in[0];
    const int*   ei  = (const int*)d_in[1];   // (2, 800000) row-major
    const float* W1l = (const float*)d_in[2];
    const float* b1l = (const float*)d_in[3];
    const float* W1r = (const float*)d_in[4];
    const float* W2l = (const float*)d_in[5];
    const float* b2l = (const float*)d_in[6];
    const float* W2r = (const float*)d_in[7];
    float* out = (float*)d_out;

    const int* src = ei;
    const int* dst = ei + N_EDGES;

    // workspace (4-byte units):
    // cursor[50176] | epad[50000*48 = 2.4M] | xh[N_PAD*128 ushort] |
    // msb[N_PAD*128 ushort] | Bp[256*128 ushort] | z[100000]
    int* cursor   = (int*)d_ws;
    int* epad     = cursor + N_PAD;
    ushort_t* xh  = (ushort_t*)(epad + N_NODES * CAP);
    ushort_t* msb = xh + (size_t)N_PAD * C;
    ushort_t* Bp  = msb + (size_t)N_PAD * C;
    float* z      = (float*)(Bp + 2 * C * C);

    hipMemsetAsync(cursor, 0, N_NODES * sizeof(int), stream);

    bucketpack_kernel<<<BUCK_B + PACK_B, 256, 0, stream>>>(
        src, dst, cursor, epad, W1l, W1r, Bp);
    tobf16_kernel<<<TOBF_B, 256, 0, stream>>>(x, xh);
    gather_kernel<<<N_NODES / 16, 256, 0, stream>>>(xh, cursor, epad, msb);
    gemm_mfma<<<392, 512, 0, stream>>>(
        msb, xh, Bp, b1l, W2l, W2r, b2l, z, out);
    final_kernel<<<N_NODES / 16, 256, 0, stream>>>(z, cursor, epad, out);
}

// Round 16
// 157.793 us; speedup vs baseline: 1.1163x; 1.1163x over previous
//
#include <hip/hip_runtime.h>

#define N_NODES 50000
#define N_PAD 50176    // 392 * 128 (gemm grid coverage)
#define N_EDGES 800000
#define C 128
#define CAP 48         // padded bucket capacity; deg ~ Poisson(16), P(>48) ~ 3e-11
#define NB 196         // coarse buckets (dst>>8), 256 nodes each
#define CBCAP 4608     // coarse bucket capacity (Poisson(4096) + 8 sigma)
#define B1_BUCK 391    // phase1 bucket blocks: 100000 threads, 8 edges each
#define TOBF_B 6250    // tobf16 blocks (1.6M float4 / 256)
#define PACK_B 16      // W-pack blocks (4096 threads)

typedef unsigned short ushort_t;
typedef unsigned int uint_t;
typedef __attribute__((ext_vector_type(8))) short bf16x8;
typedef __attribute__((ext_vector_type(4))) float f32x4;

// ---------------- fp32 -> bf16 (RNE) ----------------
__device__ __forceinline__ uint_t f2bf(float f) {
    uint_t u = __float_as_uint(f);
    u += 0x7fffu + ((u >> 16) & 1u);
    return u >> 16;
}
__device__ __forceinline__ float bflo(uint_t u) { return __uint_as_float(u << 16); }
__device__ __forceinline__ float bfhi(uint_t u) { return __uint_as_float(u & 0xffff0000u); }

// ---- phase 1: coarse-bucket edges by dst>>8 (LDS hist + 1 global atomic per
// (block,bucket)) | tobf16 fused into the same grid ----
__global__ __launch_bounds__(256) void bucket1_kernel(
    const int* __restrict__ src, const int* __restrict__ dst,
    int* __restrict__ gcur, int2* __restrict__ cb,
    const float* __restrict__ x, ushort_t* __restrict__ xh) {
    int b = blockIdx.x;
    if (b < B1_BUCK) {
        __shared__ int hist[NB];
        __shared__ int offs[NB];
        int t = threadIdx.x;
        if (t < NB) hist[t] = 0;
        __syncthreads();
        int tid = b * 256 + t;                 // 0..100095; 100000 active
        bool act = tid < N_EDGES / 8;
        int4 s0, s1, d0, d1;
        if (act) {
            s0 = ((const int4*)src)[2 * tid];
            s1 = ((const int4*)src)[2 * tid + 1];
            d0 = ((const int4*)dst)[2 * tid];
            d1 = ((const int4*)dst)[2 * tid + 1];
            atomicAdd(&hist[d0.x >> 8], 1);
            atomicAdd(&hist[d0.y >> 8], 1);
            atomicAdd(&hist[d0.z >> 8], 1);
            atomicAdd(&hist[d0.w >> 8], 1);
            atomicAdd(&hist[d1.x >> 8], 1);
            atomicAdd(&hist[d1.y >> 8], 1);
            atomicAdd(&hist[d1.z >> 8], 1);
            atomicAdd(&hist[d1.w >> 8], 1);
        }
        __syncthreads();
        if (t < NB) {
            offs[t] = atomicAdd(&gcur[t], hist[t]);   // reserve run space
            hist[t] = 0;
        }
        __syncthreads();
        if (act) {
            int ss[8] = {s0.x, s0.y, s0.z, s0.w, s1.x, s1.y, s1.z, s1.w};
            int dd[8] = {d0.x, d0.y, d0.z, d0.w, d1.x, d1.y, d1.z, d1.w};
            #pragma unroll
            for (int i = 0; i < 8; i++) {
                int bkt = dd[i] >> 8;
                int pos = offs[bkt] + atomicAdd(&hist[bkt], 1);
                if (pos < CBCAP) cb[bkt * CBCAP + pos] = make_int2(ss[i], dd[i]);
            }
        }
    } else {
        int i = (b - B1_BUCK) * 256 + threadIdx.x;   // one float4 per thread
        float4 v = ((const float4*)x)[i];
        uint_t lo = f2bf(v.x) | (f2bf(v.y) << 16);
        uint_t hi = f2bf(v.z) | (f2bf(v.w) << 16);
        ((uint2*)xh)[i] = make_uint2(lo, hi);
    }
}

// ---- phase 2: distribute each coarse bucket to per-node epad lists using LDS
// counters (L2-local writes); writes cursor[]. W-pack fused. ----
__global__ __launch_bounds__(256) void bucket2_kernel(
    const int* __restrict__ gcur, const int2* __restrict__ cb,
    int* __restrict__ cursor, int* __restrict__ epad,
    const float* __restrict__ W1l, const float* __restrict__ W1r,
    ushort_t* __restrict__ Bp) {
    int b = blockIdx.x;
    if (b < NB) {
        __shared__ int cnt[256];
        int t = threadIdx.x;
        cnt[t] = 0;
        __syncthreads();
        int lenr = gcur[b];
        int len = lenr < CBCAP ? lenr : CBCAP;
        const int2* run = cb + b * CBCAP;
        for (int e = t; e < len; e += 256) {
            int2 sd = run[e];
            int pos = atomicAdd(&cnt[sd.y & 255], 1);
            if (pos < CAP) epad[sd.y * CAP + pos] = sd.x;
        }
        __syncthreads();
        int node = b * 256 + t;
        if (node < N_NODES) cursor[node] = cnt[t];
    } else {
        // Bp[((nt*8+kk)*64 + lane)*8 + j] = Wcat[kk*32 + (lane>>4)*8 + j][nt*16 + (lane&15)]
        int p = (b - NB) * 256 + threadIdx.x;   // 0..4095
        int lane = p & 63;
        int pair = p >> 6;          // (nt*8 + kk)
        int kk = pair & 7;
        int nt = pair >> 3;
        int n = lane & 15, quad = lane >> 4;
        int col = nt * 16 + n;
        int k0 = kk * 32 + quad * 8;
        uint_t w[4];
        #pragma unroll
        for (int jj = 0; jj < 4; jj++) {
            int ka = k0 + 2 * jj, kb = k0 + 2 * jj + 1;
            float fa = (ka < C) ? W1l[ka * C + col] : W1r[(ka - C) * C + col];
            float fb = (kb < C) ? W1l[kb * C + col] : W1r[(kb - C) * C + col];
            w[jj] = f2bf(fa) | (f2bf(fb) << 16);
        }
        ((uint4*)(Bp + (size_t)p * 8))[0] = make_uint4(w[0], w[1], w[2], w[3]);
    }
}

// accumulate 8 bf16 (packed in uint4) into a[0..7] (fp32)
__device__ __forceinline__ void bf8_acc(float* a, const uint4 v) {
    a[0] += bflo(v.x); a[1] += bfhi(v.x);
    a[2] += bflo(v.y); a[3] += bfhi(v.y);
    a[4] += bflo(v.z); a[5] += bfhi(v.z);
    a[6] += bflo(v.w); a[7] += bfhi(v.w);
}

// ---------------- gather: msb[n] = mean_{j in N(n)} xh[j]  (bf16 out) ----------------
// 256 threads = 16 node-slots x 16 lanes; lane q covers cols 8q..8q+7 (uint4).
__global__ __launch_bounds__(256) void gather_kernel(const ushort_t* __restrict__ xh,
                                                     const int* __restrict__ cursor,
                                                     const int* __restrict__ epad,
                                                     ushort_t* __restrict__ msb) {
    int t = threadIdx.x;
    int slot = t >> 4, q = t & 15;
    int node = blockIdx.x * 16 + slot;   // 3125 blocks -> exactly 50000
    int d = cursor[node];
    int dd = d < CAP ? d : CAP;
    const int* lst = epad + node * CAP;
    float a[8] = {0,0,0,0,0,0,0,0};
    float b[8] = {0,0,0,0,0,0,0,0};
    int e = 0;
    for (; e + 8 <= dd; e += 8) {
        int s0 = lst[e + 0], s1 = lst[e + 1], s2 = lst[e + 2], s3 = lst[e + 3];
        int s4 = lst[e + 4], s5 = lst[e + 5], s6 = lst[e + 6], s7 = lst[e + 7];
        uint4 v0 = ((const uint4*)(xh + (size_t)s0 * C))[q];
        uint4 v1 = ((const uint4*)(xh + (size_t)s1 * C))[q];
        uint4 v2 = ((const uint4*)(xh + (size_t)s2 * C))[q];
        uint4 v3 = ((const uint4*)(xh + (size_t)s3 * C))[q];
        uint4 v4 = ((const uint4*)(xh + (size_t)s4 * C))[q];
        uint4 v5 = ((const uint4*)(xh + (size_t)s5 * C))[q];
        uint4 v6 = ((const uint4*)(xh + (size_t)s6 * C))[q];
        uint4 v7 = ((const uint4*)(xh + (size_t)s7 * C))[q];
        bf8_acc(a, v0); bf8_acc(b, v1); bf8_acc(a, v2); bf8_acc(b, v3);
        bf8_acc(a, v4); bf8_acc(b, v5); bf8_acc(a, v6); bf8_acc(b, v7);
    }
    for (; e + 4 <= dd; e += 4) {
        int s0 = lst[e + 0], s1 = lst[e + 1], s2 = lst[e + 2], s3 = lst[e + 3];
        uint4 v0 = ((const uint4*)(xh + (size_t)s0 * C))[q];
        uint4 v1 = ((const uint4*)(xh + (size_t)s1 * C))[q];
        uint4 v2 = ((const uint4*)(xh + (size_t)s2 * C))[q];
        uint4 v3 = ((const uint4*)(xh + (size_t)s3 * C))[q];
        bf8_acc(a, v0); bf8_acc(b, v1); bf8_acc(a, v2); bf8_acc(b, v3);
    }
    for (; e < dd; e++) {
        uint4 v = ((const uint4*)(xh + (size_t)lst[e] * C))[q];
        bf8_acc(a, v);
    }
    float inv = 1.0f / fmaxf((float)d, 1.0f);
    uint4 o;
    o.x = f2bf((a[0] + b[0]) * inv) | (f2bf((a[1] + b[1]) * inv) << 16);
    o.y = f2bf((a[2] + b[2]) * inv) | (f2bf((a[3] + b[3]) * inv) << 16);
    o.z = f2bf((a[4] + b[4]) * inv) | (f2bf((a[5] + b[5]) * inv) << 16);
    o.w = f2bf((a[6] + b[6]) * inv) | (f2bf((a[7] + b[7]) * inv) << 16);
    ((uint4*)(msb + (size_t)node * C))[q] = o;
}

// ---------------- gemm (MFMA, LDS-staged B): h = relu([ms|xs]@[W1l;W1r]+b1l) ----------------
__global__ __launch_bounds__(512) void gemm_mfma(
    const ushort_t* __restrict__ msb, const ushort_t* __restrict__ xh,
    const ushort_t* __restrict__ Bp, const float* __restrict__ b1l,
    const float* __restrict__ W2l, const float* __restrict__ W2r,
    const float* __restrict__ b2l, float* __restrict__ z, float* __restrict__ out) {
    __shared__ ushort_t sB[2 * C * C];   // 64 KB
    int t = threadIdx.x;
    #pragma unroll
    for (int i = 0; i < 8; i++)
        ((uint4*)sB)[i * 512 + t] = ((const uint4*)Bp)[i * 512 + t];
    __syncthreads();

    int wid = t >> 6, lane = t & 63;
    int m = lane & 15, quad = lane >> 4;
    int base = blockIdx.x * 128 + wid * 16;   // node base for this wave

    const ushort_t* a_ms = msb + (size_t)(base + m) * C + quad * 8;
    const ushort_t* a_xh = xh  + (size_t)(base + m) * C + quad * 8;
    bf16x8 aw[8];
    #pragma unroll
    for (int kk = 0; kk < 4; kk++) aw[kk]     = *(const bf16x8*)(a_ms + kk * 32);
    #pragma unroll
    for (int kk = 0; kk < 4; kk++) aw[4 + kk] = *(const bf16x8*)(a_xh + kk * 32);

    f32x4 acc[8];
    #pragma unroll
    for (int nt = 0; nt < 8; nt++) acc[nt] = (f32x4){0.f, 0.f, 0.f, 0.f};

    const bf16x8* bp = (const bf16x8*)sB;
    #pragma unroll
    for (int kk = 0; kk < 8; kk++) {
        bf16x8 a = aw[kk];
        #pragma unroll
        for (int nt = 0; nt < 8; nt++) {
            bf16x8 bfr = bp[(nt * 8 + kk) * 64 + lane];   // ds_read_b128
            acc[nt] = __builtin_amdgcn_mfma_f32_16x16x32_bf16(a, bfr, acc[nt], 0, 0, 0);
        }
    }

    float zz0[4] = {0,0,0,0}, zz1[4] = {0,0,0,0};
    float rr0[4] = {0,0,0,0}, rr1[4] = {0,0,0,0};
    #pragma unroll
    for (int nt = 0; nt < 8; nt++) {
        int col = nt * 16 + m;
        float bias = b1l[col];
        float2 wl = ((const float2*)W2l)[col];
        float2 wr = ((const float2*)W2r)[col];
        #pragma unroll
        for (int reg = 0; reg < 4; reg++) {
            float h = fmaxf(acc[nt][reg] + bias, 0.0f);
            zz0[reg] = fmaf(h, wl.x, zz0[reg]);
            zz1[reg] = fmaf(h, wl.y, zz1[reg]);
            rr0[reg] = fmaf(h, wr.x, rr0[reg]);
            rr1[reg] = fmaf(h, wr.y, rr1[reg]);
        }
    }
    float bl0 = b2l[0], bl1 = b2l[1];
    #pragma unroll
    for (int reg = 0; reg < 4; reg++) {
        float a0 = zz0[reg], a1 = zz1[reg], c0 = rr0[reg], c1 = rr1[reg];
        #pragma unroll
        for (int off = 8; off > 0; off >>= 1) {
            a0 += __shfl_down(a0, off, 16);
            a1 += __shfl_down(a1, off, 16);
            c0 += __shfl_down(c0, off, 16);
            c1 += __shfl_down(c1, off, 16);
        }
        if (m == 0) {
            int node = base + quad * 4 + reg;
            if (node < N_NODES) {
                z[node * 2 + 0]   = a0;
                z[node * 2 + 1]   = a1;
                out[node * 2 + 0] = c0 + bl0;
                out[node * 2 + 1] = c1 + bl1;
            }
        }
    }
}

// ---------------- final: out[n] += mean_{j in N(n)} z[j], 16 lanes per node ----------------
__global__ __launch_bounds__(256) void final_kernel(const float* __restrict__ z,
                                                    const int* __restrict__ cursor,
                                                    const int* __restrict__ epad,
                                                    float* __restrict__ out) {
    int t = threadIdx.x;
    int sub = t & 15;
    int node = blockIdx.x * 16 + (t >> 4);   // 3125 blocks
    int d = cursor[node];
    int dd = d < CAP ? d : CAP;
    const int* lst = epad + node * CAP;
    float a0 = 0.0f, a1 = 0.0f;
    for (int e = sub; e < dd; e += 16) {
        float2 v = ((const float2*)z)[lst[e]];
        a0 += v.x; a1 += v.y;
    }
    #pragma unroll
    for (int off = 8; off > 0; off >>= 1) {
        a0 += __shfl_down(a0, off);
        a1 += __shfl_down(a1, off);
    }
    if (sub == 0) {
        float inv = 1.0f / fmaxf((float)d, 1.0f);
        out[node * 2 + 0] += a0 * inv;
        out[node * 2 + 1] += a1 * inv;
    }
}

extern "C" void kernel_launch(void* const* d_in, const int* in_sizes, int n_in,
                              void* d_out, int out_size, void* d_ws, size_t ws_size,
                              hipStream_t stream) {
    const float* x   = (const float*)d_in[0];
    const int*   ei  = (const int*)d_in[1];   // (2, 800000) row-major
    const float* W1l = (const float*)d_in[2];
    const float* b1l = (const float*)d_in[3];
    const float* W1r = (const float*)d_in[4];
    const float* W2l = (const float*)d_in[5];
    const float* b2l = (const float*)d_in[6];
    const float* W2r = (const float*)d_in[7];
    float* out = (float*)d_out;

    const int* src = ei;
    const int* dst = ei + N_EDGES;

    // workspace (4-byte units):
    // gcur[256] | cb[NB*CBCAP int2 = 1.81M x2] | cursor[50176] |
    // epad[50000*48 = 2.4M] | xh[N_PAD*128 ushort] | msb[...] | Bp | z
    int* gcur     = (int*)d_ws;
    int2* cb      = (int2*)(gcur + 256);
    int* cursor   = (int*)(cb + NB * CBCAP);
    int* epad     = cursor + N_PAD;
    ushort_t* xh  = (ushort_t*)(epad + N_NODES * CAP);
    ushort_t* msb = xh + (size_t)N_PAD * C;
    ushort_t* Bp  = msb + (size_t)N_PAD * C;
    float* z      = (float*)(Bp + 2 * C * C);

    hipMemsetAsync(gcur, 0, NB * sizeof(int), stream);

    bucket1_kernel<<<B1_BUCK + TOBF_B, 256, 0, stream>>>(src, dst, gcur, cb, x, xh);
    bucket2_kernel<<<NB + PACK_B, 256, 0, stream>>>(gcur, cb, cursor, epad, W1l, W1r, Bp);
    gather_kernel<<<N_NODES / 16, 256, 0, stream>>>(xh, cursor, epad, msb);
    gemm_mfma<<<392, 512, 0, stream>>>(msb, xh, Bp, b1l, W2l, W2r, b2l, z, out);
    final_kernel<<<N_NODES / 16, 256, 0, stream>>>(z, cursor, epad, out);
}